// Round 7
// baseline (1790.869 us; speedup 1.0000x reference)
//
#include <hip/hip_runtime.h>
#include <hip/hip_bf16.h>

typedef __attribute__((ext_vector_type(8))) short short8v;
typedef __attribute__((ext_vector_type(4))) short short4v;
typedef __attribute__((ext_vector_type(4))) float float4v;

__device__ __forceinline__ unsigned short f2bu(float v){
  __hip_bfloat16 h = __float2bfloat16(v);
  union { __hip_bfloat16 h; unsigned short u; } cv; cv.h = h; return cv.u;
}

// soft(v, lam) = sign(v) * max(|v| - lam, 0)   (lam may be negative)
__device__ __forceinline__ float softt(float v, float lam){
  float t = fmaxf(fabsf(v) - lam, 0.f);
  float r = copysignf(t, v);
  return (v == 0.f) ? 0.f : r;
}

// L scalar (f32 input)
__global__ void k_Lin(const float* __restrict__ Lsrc, float* __restrict__ Lb){
  Lb[0] = Lsrc[0];
}

// Gram in bf16: Gb[j][a] = bf16(sum_c D[c][j]*D[c][a]).
__global__ void k_gram(const float* __restrict__ D, unsigned short* __restrict__ Gb){
  int j = blockIdx.x, a = threadIdx.x;
  float acc = 0.f;
  for (int c = 0; c < 64; ++c)
    acc += D[c*256 + j] * D[c*256 + a];
  Gb[j*256 + a] = f2bu(acc);
}

// DT[a][c] = D[c][a] (f32 for recon) + bf16 copy
__global__ void k_transpD(const float* __restrict__ D, float* __restrict__ DT,
                          unsigned short* __restrict__ DTb){
  int gid = blockIdx.x * 256 + threadIdx.x;     // gid = a*64 + c
  if (gid < 16384) {
    int a = gid >> 6, c = gid & 63;
    float v = D[c*256 + a];
    DT[gid] = v;
    DTb[gid] = f2bu(v);
  }
}

// fp32 -> bf16 cast (1x1 conv weights [O][I], and x -> xb)
__global__ void k_castw(const float* __restrict__ w, unsigned short* __restrict__ wb,
                        int n){
  int gid = blockIdx.x * 256 + threadIdx.x;
  if (gid < n) wb[gid] = f2bu(w[gid]);
}

// 3x3 conv weights OIHW f32 -> tap-major bf16 [O][9][I]
__global__ void k_permw3(const float* __restrict__ w, unsigned short* __restrict__ wb,
                         int logI, int n){
  int gid = blockIdx.x * 256 + threadIdx.x;
  if (gid >= n) return;
  int I = 1 << logI;
  int i = gid & (I - 1);
  int t = gid >> logI;        // o*9 + r
  int o = t / 9;
  int r = t - o * 9;
  wb[gid] = f2bu(w[((o << logI) + i) * 9 + r]);
}

// ---------------------------------------------------------------------------
// MFMA implicit-GEMM conv: bf16 activations (relu pre-applied by producer),
// tap-major bf16 weights [O][KS*KS][CIN], fp32 accumulate.
// BM=64 (one image row), BN=128, BK=64, 256 threads / 4 waves.
// 16 MFMA + 12 ds_read_b128 per barrier-pair (vs 8+6 at BK=32): half the
// barriers per MFMA -> amortizes the global-prefetch latency drain.
// K-slice order within a step == old two-step order -> bitwise-identical acc.
// 1-deep register prefetch; XCD-aware block swizzle (grid.x % 8 == 0).
// ---------------------------------------------------------------------------
template<int KS, int CIN, bool BIAS, bool RES, bool WF32, bool WBF>
__global__ __launch_bounds__(256) void k_conv(
    const unsigned short* __restrict__ in, const unsigned short* __restrict__ wb,
    const float* __restrict__ bias, const float* res, float* outf,
    unsigned short* __restrict__ outb, int Cout)
{
  constexpr int TPC = CIN / 64;              // 64-wide k-chunks per tap
  constexpr int K   = KS * KS * CIN;

  __shared__ unsigned short Asb[64][72];     // row stride 144 B
  __shared__ unsigned short Bsb[128][72];

  const int tid = threadIdx.x;
  int bx = blockIdx.x;
  { const int cpx = gridDim.x >> 3; bx = (bx & 7) * cpx + (bx >> 3); }
  const int m0  = bx * 64;
  const int n0  = blockIdx.y * 128;
  const int b   = m0 >> 12;
  const int hw0 = m0 & 4095;
  const int h   = hw0 >> 6;
  const int w0  = hw0 & 63;

  // staging assignments
  const int sm  = tid & 63;                  // A row (m, spatial w)
  const int sq8 = tid >> 6;                  // A 8-k chunk 0..3 (+4 for hi half)
  const int bn  = tid & 127;                 // B row (n-local)
  const int bq  = tid >> 7;                  // 0..1 -> 32-k half

  // MFMA lane mapping
  const int w   = tid >> 6;                  // wave 0..3 -> n-range w*32..+32
  const int ln  = tid & 63;
  const int q   = ln >> 4;
  const int l16 = ln & 15;

  float4v acc[2][4];
  #pragma unroll
  for (int nt = 0; nt < 2; ++nt)
    #pragma unroll
    for (int mt = 0; mt < 4; ++mt)
      acc[nt][mt] = (float4v){0.f, 0.f, 0.f, 0.f};

  int sA = 0, sB = TPC;
  if (KS == 3) { sA = (h == 0 ? 3 : 0) * TPC; sB = (h == 63 ? 6 : 9) * TPC; }

  short8v a_r0, a_r1;
  short8v b_r0, b_r1, b_r2, b_r3;

  auto pref = [&](int s){
    const int r   = s / TPC;                 // tap (TPC is constexpr pow2)
    const int c64 = s - r * TPC;
    int hh = h, ww = w0 + sm;
    bool ok = true;
    if (KS == 3) {
      const int r3 = r / 3;
      const int dw = r - r3 * 3 - 1;
      hh = h + r3 - 1;
      ww += dw;
      ok = ((unsigned)ww < 64u);
    }
    a_r0 = (short8v){0,0,0,0,0,0,0,0};
    a_r1 = (short8v){0,0,0,0,0,0,0,0};
    if (ok) {
      const unsigned short* ap = in +
          (((size_t)(b * CIN + c64 * 64 + sq8 * 8)) << 12) + (hh << 6) + ww;
      #pragma unroll
      for (int j = 0; j < 8; ++j)
        a_r0[j] = (short)ap[(size_t)j << 12];
      const unsigned short* ap2 = ap + ((size_t)32 << 12);
      #pragma unroll
      for (int j = 0; j < 8; ++j)
        a_r1[j] = (short)ap2[(size_t)j << 12];
    }
    const unsigned short* bp = wb + (size_t)(n0 + bn) * K + s * 64 + bq * 32;
    b_r0 = *(const short8v*)(bp);
    b_r1 = *(const short8v*)(bp + 8);
    b_r2 = *(const short8v*)(bp + 16);
    b_r3 = *(const short8v*)(bp + 24);
  };

  pref(sA);
  for (int s = sA; s < sB; ) {
    // commit prefetched tile to LDS
    *(short8v*)(&Asb[sm][sq8 * 8])       = a_r0;
    *(short8v*)(&Asb[sm][32 + sq8 * 8])  = a_r1;
    *(short8v*)(&Bsb[bn][bq * 32])       = b_r0;
    *(short8v*)(&Bsb[bn][bq * 32 + 8])   = b_r1;
    *(short8v*)(&Bsb[bn][bq * 32 + 16])  = b_r2;
    *(short8v*)(&Bsb[bn][bq * 32 + 24])  = b_r3;
    __syncthreads();
    const int sn = s + 1;
    if (sn < sB) pref(sn);               // loads in flight across the MFMAs
    short8v Af[4][2];
    #pragma unroll
    for (int mt = 0; mt < 4; ++mt) {
      Af[mt][0] = *(const short8v*)(&Asb[mt * 16 + l16][q * 8]);
      Af[mt][1] = *(const short8v*)(&Asb[mt * 16 + l16][32 + q * 8]);
    }
    #pragma unroll
    for (int nt = 0; nt < 2; ++nt) {
      const short8v Bf0 = *(const short8v*)(&Bsb[w * 32 + nt * 16 + l16][q * 8]);
      const short8v Bf1 = *(const short8v*)(&Bsb[w * 32 + nt * 16 + l16][32 + q * 8]);
      #pragma unroll
      for (int mt = 0; mt < 4; ++mt) {
        acc[nt][mt] = __builtin_amdgcn_mfma_f32_16x16x32_bf16(
            Af[mt][0], Bf0, acc[nt][mt], 0, 0, 0);
        acc[nt][mt] = __builtin_amdgcn_mfma_f32_16x16x32_bf16(
            Af[mt][1], Bf1, acc[nt][mt], 0, 0, 0);
      }
    }
    __syncthreads();
    s = sn;
  }

  // ---- epilogue: C row=q*4+r (spatial m), col=l16 (n)
  #pragma unroll
  for (int nt = 0; nt < 2; ++nt) {
    const int n = n0 + w * 32 + nt * 16 + l16;
    float bv = 0.f;
    if (BIAS) bv = bias[n];
    #pragma unroll
    for (int mt = 0; mt < 4; ++mt) {
      const size_t base = (((size_t)(b * Cout + n)) << 12) + hw0 + mt * 16 + q * 4;
      float o[4];
      #pragma unroll
      for (int r2 = 0; r2 < 4; ++r2) o[r2] = acc[nt][mt][r2] + bv;
      if (RES) {
        float4 r4 = *(const float4*)(res + base);
        o[0] += r4.x; o[1] += r4.y; o[2] += r4.z; o[3] += r4.w;
      }
      if (WF32) {
        float4 o4; o4.x = o[0]; o4.y = o[1]; o4.z = o[2]; o4.w = o[3];
        *(float4*)(outf + base) = o4;
      }
      if (WBF) {
        short4v s4;
        #pragma unroll
        for (int r2 = 0; r2 < 4; ++r2) s4[r2] = (short)f2bu(fmaxf(o[r2], 0.f));
        *(short4v*)(outb + base) = s4;
      }
    }
  }
}

// ---------------------------------------------------------------------------
// CBAM
// ---------------------------------------------------------------------------
__global__ void k_pool(const float* __restrict__ l, float* __restrict__ avg,
                       float* __restrict__ mx){
  int b = blockIdx.y, a = blockIdx.x, tid = threadIdx.x;
  const float* p = l + ((size_t)(b * 256 + a) << 12);
  float s = 0.f, m = -1e30f;
  for (int i = tid; i < 4096; i += 256) { float v = p[i]; s += v; m = fmaxf(m, v); }
  __shared__ float ss[256], sm[256];
  ss[tid] = s; sm[tid] = m; __syncthreads();
  for (int o = 128; o > 0; o >>= 1) {
    if (tid < o) { ss[tid] += ss[tid+o]; sm[tid] = fmaxf(sm[tid], sm[tid+o]); }
    __syncthreads();
  }
  if (tid == 0) { avg[b*256+a] = ss[0] * (1.f/4096.f); mx[b*256+a] = sm[0]; }
}

__global__ void k_ca(const float* __restrict__ avg, const float* __restrict__ mx,
                     const float* __restrict__ w1, const float* __restrict__ w2,
                     float* __restrict__ cscale){
  int b = blockIdx.x, tid = threadIdx.x;
  __shared__ float h[16];
  if (tid < 16) {
    float sa = 0.f, sm = 0.f;
    for (int a = 0; a < 256; ++a) {
      float w = w1[tid*256 + a];
      sa += avg[b*256 + a] * w;
      sm += mx[b*256 + a] * w;
    }
    h[tid] = fmaxf(sa, 0.f) + fmaxf(sm, 0.f);
  }
  __syncthreads();
  float s = 0.f;
  for (int j = 0; j < 16; ++j) s += h[j] * w2[tid*16 + j];
  cscale[b*256 + tid] = 1.f / (1.f + __expf(-s));
}

__global__ void k_s2(const float* __restrict__ l, const float* __restrict__ cscale,
                     float* __restrict__ s2){
  int b = blockIdx.y;
  int hw = blockIdx.x * 256 + threadIdx.x;
  const float* p  = l + (((size_t)b * 256) << 12) + hw;
  const float* cs = cscale + b * 256;
  float s = 0.f, m = -1e30f;
  for (int a = 0; a < 256; ++a) {
    float v = p[(size_t)a << 12] * cs[a];
    s += v; m = fmaxf(m, v);
  }
  s2[((b*2) << 12) + hw]   = s * (1.f/256.f);
  s2[((b*2+1) << 12) + hw] = m;
}

__global__ void k_sa(const float* __restrict__ s2, const float* __restrict__ w,
                     float* __restrict__ sa){
  int b = blockIdx.y;
  int hw = blockIdx.x * 256 + threadIdx.x;
  int h = hw >> 6, ww = hw & 63;
  float acc = 0.f;
  for (int ch = 0; ch < 2; ++ch)
    for (int dh = -1; dh <= 1; ++dh)
      for (int dw = -1; dw <= 1; ++dw) {
        int hh = h + dh, wc = ww + dw;
        if ((unsigned)hh < 64u && (unsigned)wc < 64u)
          acc += s2[((b*2+ch) << 12) + (hh << 6) + wc] * w[ch*9 + (dh+1)*3 + (dw+1)];
      }
  sa[(b << 12) + hw] = 1.f / (1.f + __expf(-acc));
}

// ---------------------------------------------------------------------------
// FUSED LISTA v7 (transposed): C' = S . z^T, S symmetric.
// Tile = 16 positions x 256 atoms; 256 threads / 4 waves; wave owns 64 ATOMS.
// __launch_bounds__(256,4): VGPR cap 128 (current use 116) -> 4 blocks/CU
// resident (vs 2), so independent blocks' MFMA/VALU phases overlap.
// s_setprio(1) around the MFMA cluster (blocks per CU are desynchronized).
// Sg pinned via in-loop asm; zbuf 512B rows + XOR-8 chunk swizzle.
// ---------------------------------------------------------------------------
#define XTS 80

__device__ __forceinline__ int zoff(int pos, int au8){
  return pos * 256 + (((au8 ^ (pos & 15)) & 31) << 3);
}

__global__ __launch_bounds__(256, 4) void k_lista(
    const unsigned short* __restrict__ xb,
    const unsigned short* __restrict__ DTb,
    const unsigned short* __restrict__ Gb,
    const float* __restrict__ lmap, const float* __restrict__ csc,
    const float* __restrict__ sav, const float* __restrict__ Lb,
    float* __restrict__ zout)
{
  __shared__ unsigned short zbuf[2][16 * 256];   // 16 KB total

  const int tid = threadIdx.x;
  const int m0  = blockIdx.x * 16;
  const int b   = m0 >> 12;
  const int hw0 = m0 & 4095;
  const float invL = 1.0f / Lb[0];

  // stage x tile (bf16, transposed) into zbuf[1] space: xTb[i*XTS + c]
  unsigned short* xTb = &zbuf[1][0];
  {
    const int i  = tid & 15;
    const int c0 = tid >> 4;          // 0..15
    #pragma unroll
    for (int cc = 0; cc < 4; ++cc) {
      int c = c0 + cc * 16;
      xTb[i * XTS + c] = xb[((b * 64 + c) << 12) + hw0 + i];
    }
  }

  const int w   = tid >> 6;           // wave 0..3 -> atoms w*64..w*64+63
  const int ln  = tid & 63;
  const int q   = ln >> 4;
  const int l16 = ln & 15;

  // persistent Gram A-fragments: 4 x 16-atom blocks x K=256 (128 VGPRs)
  short8v Sg[4][8];
  #pragma unroll
  for (int at = 0; at < 4; ++at)
    #pragma unroll
    for (int ks = 0; ks < 8; ++ks)
      Sg[at][ks] = *(const short8v*)(
          Gb + (size_t)(w * 64 + at * 16 + l16) * 256 + ks * 32 + q * 8);

  __syncthreads();   // xTb ready

  float z[4][4], yl[4][4], lamr[4][4];   // [at][r]

  // ---- prologue: y^T = D^T x^T ; lam fused ; z0 -> zbuf[0]
  {
    const short8v B0 = *(const short8v*)(&xTb[l16 * XTS + q * 8]);
    const short8v B1 = *(const short8v*)(&xTb[l16 * XTS + 32 + q * 8]);
    #pragma unroll
    for (int at = 0; at < 4; ++at) {
      const int abase = w * 64 + at * 16;
      const short8v A0 = *(const short8v*)(DTb + (abase + l16) * 64 + q * 8);
      const short8v A1 = *(const short8v*)(DTb + (abase + l16) * 64 + 32 + q * 8);
      float4v a = {0.f, 0.f, 0.f, 0.f};
      a = __builtin_amdgcn_mfma_f32_16x16x32_bf16(A0, B0, a, 0, 0, 0);
      a = __builtin_amdgcn_mfma_f32_16x16x32_bf16(A1, B1, a, 0, 0, 0);
      short4v pk;
      #pragma unroll
      for (int r = 0; r < 4; ++r) {
        const int atom = abase + q * 4 + r;
        const float lv = lmap[(((size_t)(b * 256 + atom)) << 12) + hw0 + l16];
        const float sv = sav[(b << 12) + hw0 + l16];
        const float cv = csc[b * 256 + atom];
        const float lm = ((lv * cv) * sv) * invL;   // same op order as before
        const float yv = a[r];
        lamr[at][r] = lm;
        yl[at][r]   = yv * invL;
        const float z0 = softt(yv, lm);
        z[at][r] = z0;
        pk[r] = (short)f2bu(z0);
      }
      *(short4v*)(&zbuf[0][zoff(l16, w * 8 + at * 2 + (q >> 1)) + (q & 1) * 4]) = pk;
    }
  }
  __syncthreads();

  int cur = 0;
  for (int it = 0; it < 16; ++it) {
    // pin Sg every iteration: reload-from-Gb would break the asm dataflow
    #pragma unroll
    for (int at = 0; at < 4; ++at)
      #pragma unroll
      for (int ks = 0; ks < 8; ++ks)
        asm volatile("" : "+v"(Sg[at][ks]));

    float4v acc[4];
    #pragma unroll
    for (int at = 0; at < 4; ++at)
      acc[at] = (float4v){0.f, 0.f, 0.f, 0.f};

    __builtin_amdgcn_s_setprio(1);
    #pragma unroll
    for (int ks = 0; ks < 8; ++ks) {
      const short8v B = *(const short8v*)(&zbuf[cur][zoff(l16, ks * 4 + q)]);
      acc[0] = __builtin_amdgcn_mfma_f32_16x16x32_bf16(Sg[0][ks], B, acc[0], 0, 0, 0);
      acc[1] = __builtin_amdgcn_mfma_f32_16x16x32_bf16(Sg[1][ks], B, acc[1], 0, 0, 0);
      acc[2] = __builtin_amdgcn_mfma_f32_16x16x32_bf16(Sg[2][ks], B, acc[2], 0, 0, 0);
      acc[3] = __builtin_amdgcn_mfma_f32_16x16x32_bf16(Sg[3][ks], B, acc[3], 0, 0, 0);
    }
    __builtin_amdgcn_s_setprio(0);

    #pragma unroll
    for (int at = 0; at < 4; ++at) {
      short4v pk;
      #pragma unroll
      for (int r = 0; r < 4; ++r) {
        const float u  = fmaf(-invL, acc[at][r], z[at][r] + yl[at][r]);
        const float nz = softt(u, lamr[at][r]);
        z[at][r] = nz;
        pk[r] = (short)f2bu(nz);
      }
      *(short4v*)(&zbuf[cur ^ 1][zoff(l16, w * 8 + at * 2 + (q >> 1)) + (q & 1) * 4]) = pk;
    }
    __syncthreads();
    cur ^= 1;
  }

  // ---- store z (f32, row-major [p][a]) as float4 (4 consecutive atoms)
  #pragma unroll
  for (int at = 0; at < 4; ++at) {
    float4 o;
    o.x = z[at][0]; o.y = z[at][1]; o.z = z[at][2]; o.w = z[at][3];
    *(float4*)(&zout[(size_t)(m0 + l16) * 256 + w * 64 + at * 16 + q * 4]) = o;
  }
}

// x_recon[p][c] = sum_a z[p][a] * DT[a][c]  -> f32 NCHW output
__global__ __launch_bounds__(256) void k_recon_simple(
    const float* __restrict__ z, const float* __restrict__ DT,
    float* __restrict__ out1)
{
  __shared__ float zs[16][256];
  const int tid = threadIdx.x;
  const int r0  = blockIdx.x * 16;
  const int b   = r0 >> 12;
  const int hw0 = r0 & 4095;

  for (int idx = tid; idx < 4096; idx += 256) {
    int r = idx >> 8, k = idx & 255;
    zs[r][k] = z[(r0 + r) * 256 + k];
  }
  __syncthreads();

  const int c  = tid & 63;
  const int rg = tid >> 6;
  float acc[4] = {0.f, 0.f, 0.f, 0.f};
  for (int a = 0; a < 256; ++a) {
    float d = DT[a * 64 + c];
    #pragma unroll
    for (int i = 0; i < 4; ++i) acc[i] += zs[rg + 4*i][a] * d;
  }
  #pragma unroll
  for (int i = 0; i < 4; ++i) {
    int r = rg + 4*i;
    out1[((b * 64 + c) << 12) + hw0 + r] = acc[i];
  }
}

// z [p][a] f32 -> out0 f32 [b][a][hw], LDS-tiled 64x64 transpose
__global__ __launch_bounds__(256) void k_zout_t(const float* __restrict__ z,
                                                float* __restrict__ out0){
  __shared__ float zs[64][65];
  const int tid = threadIdx.x;
  const int hwt = blockIdx.x * 64;
  const int at  = blockIdx.y * 64;
  const int b   = blockIdx.z;
  const int j   = tid & 63;
  const int i0  = tid >> 6;
  #pragma unroll
  for (int k = 0; k < 16; ++k) {
    int i = i0 + k * 4;                      // hw-local row
    zs[i][j] = z[(size_t)(b * 4096 + hwt + i) * 256 + at + j];
  }
  __syncthreads();
  #pragma unroll
  for (int k = 0; k < 16; ++k) {
    int i = i0 + k * 4;                      // a-local row
    out0[(((size_t)(b * 256 + at + i)) << 12) + hwt + j] = zs[j][i];
  }
}

__global__ void k_dictout_f32(const float* __restrict__ D, float* __restrict__ out2){
  int i = blockIdx.x * 256 + threadIdx.x;
  if (i < 16384) out2[i] = D[i];
}

// ---------------------------------------------------------------------------
extern "C" void kernel_launch(void* const* d_in, const int* in_sizes, int n_in,
                              void* d_out, int out_size, void* d_ws, size_t ws_size,
                              hipStream_t stream)
{
  (void)in_sizes; (void)n_in; (void)out_size; (void)ws_size;

  const float* x    = (const float*)d_in[0];
  const float* cw   = (const float*)d_in[1];
  const float* cb   = (const float*)d_in[2];
  const float* r1w1 = (const float*)d_in[3];
  const float* r1w2 = (const float*)d_in[4];
  const float* r2w1 = (const float*)d_in[5];
  const float* r2w2 = (const float*)d_in[6];
  const float* caw1 = (const float*)d_in[7];
  const float* caw2 = (const float*)d_in[8];
  const float* saw  = (const float*)d_in[9];
  const float* D    = (const float*)d_in[10];
  const float* Lsrc = (const float*)d_in[11];

  float* p = (float*)d_ws;
  float* DT   = p; p += 16384;
  float* Lb   = p; p += 8;
  unsigned short* Gb  = (unsigned short*)p; p += 32768;   // 65536 bf16
  unsigned short* DTb = (unsigned short*)p; p += 8192;    // 16384 bf16
  unsigned short* cwb   = (unsigned short*)p; p += 73728;   // [256][9][64]
  unsigned short* r1w1b = (unsigned short*)p; p += 147456;  // [128][9][256]
  unsigned short* r1w2b = (unsigned short*)p; p += 16384;   // [256][128]
  unsigned short* r2w1b = (unsigned short*)p; p += 147456;
  unsigned short* r2w2b = (unsigned short*)p; p += 16384;
  float* avg  = p; p += 2048;
  float* mx   = p; p += 2048;
  float* csc  = p; p += 2048;
  float* s2   = p; p += 65536;
  float* sa   = p; p += 32768;
  float* l    = p; p += 8388608;
  float* scr  = p; p += 8388608;   // bf16 activation scratch region
  float* zt   = p; p += 8388608;   // final z
  float* z    = zt;

  // bf16 activation scratch (dead by the time k_lista runs, except xb which
  // is only ever written once by k_castw):
  unsigned short* xb = (unsigned short*)scr;                       // 2,097,152 u16
  unsigned short* lb = (unsigned short*)(scr + 1048576);           // 8,388,608 u16
  unsigned short* tb = (unsigned short*)(scr + 1048576 + 4194304); // 4,194,304 u16

  float* out0 = (float*)d_out;               // z       [8,256,64,64]
  float* out1 = out0 + (size_t)8*256*4096;   // x_recon [8,64,64,64]
  float* out2 = out1 + (size_t)8*64*4096;    // Dict    [64,256]

  dim3 b256(256);

  k_Lin<<<dim3(1), dim3(1), 0, stream>>>(Lsrc, Lb);
  k_gram<<<dim3(256), b256, 0, stream>>>(D, Gb);
  k_transpD<<<dim3(64), b256, 0, stream>>>(D, DT, DTb);
  // weights: 3x3 -> tap-major bf16, 1x1 -> plain bf16; x -> bf16
  k_permw3<<<dim3(576),  b256, 0, stream>>>(cw,   cwb,   6, 147456);
  k_permw3<<<dim3(1152), b256, 0, stream>>>(r1w1, r1w1b, 8, 294912);
  k_castw <<<dim3(128),  b256, 0, stream>>>(r1w2, r1w2b, 32768);
  k_permw3<<<dim3(1152), b256, 0, stream>>>(r2w1, r2w1b, 8, 294912);
  k_castw <<<dim3(128),  b256, 0, stream>>>(r2w2, r2w2b, 32768);
  k_castw <<<dim3(8192), b256, 0, stream>>>(x, xb, 2097152);

  // conv trunk (bf16 MFMA, tap-major weights, bf16 activation chain, BK=64)
  k_conv<3,  64, true,  false, true,  true ><<<dim3(512, 2), b256, 0, stream>>>(
      xb, cwb, cb, (const float*)nullptr, l, lb, 256);
  k_conv<3, 256, false, false, false, true ><<<dim3(512, 1), b256, 0, stream>>>(
      lb, r1w1b, (const float*)nullptr, (const float*)nullptr, (float*)nullptr, tb, 128);
  k_conv<1, 128, false, true,  true,  true ><<<dim3(512, 2), b256, 0, stream>>>(
      tb, r1w2b, (const float*)nullptr, l, l, lb, 256);
  k_conv<3, 256, false, false, false, true ><<<dim3(512, 1), b256, 0, stream>>>(
      lb, r2w1b, (const float*)nullptr, (const float*)nullptr, (float*)nullptr, tb, 128);
  k_conv<1, 128, false, true,  true,  false><<<dim3(512, 2), b256, 0, stream>>>(
      tb, r2w2b, (const float*)nullptr, l, l, (unsigned short*)nullptr, 256);

  // CBAM
  k_pool<<<dim3(256, 8), b256, 0, stream>>>(l, avg, mx);
  k_ca<<<dim3(8), b256, 0, stream>>>(avg, mx, caw1, caw2, csc);
  k_s2<<<dim3(16, 8), b256, 0, stream>>>(l, csc, s2);
  k_sa<<<dim3(16, 8), b256, 0, stream>>>(s2, saw, sa);

  // FUSED LISTA (transposed; lam fused inside; 256 threads, 4 waves, 64
  // atoms/wave, Sg register-resident, 4 blocks/CU)
  k_lista<<<dim3(2048), b256, 0, stream>>>(xb, DTb, Gb, l, csc, sa, Lb, z);

  // outputs (float32)
  k_recon_simple<<<dim3(2048), b256, 0, stream>>>(z, DT, out1);
  k_zout_t<<<dim3(64, 4, 8), b256, 0, stream>>>(z, out0);
  k_dictout_f32<<<dim3(64), b256, 0, stream>>>(D, out2);
}

// Round 8
// 473.665 us; speedup vs baseline: 3.7809x; 3.7809x over previous
//
#include <hip/hip_runtime.h>
#include <hip/hip_bf16.h>

typedef __attribute__((ext_vector_type(8))) short short8v;
typedef __attribute__((ext_vector_type(4))) short short4v;
typedef __attribute__((ext_vector_type(4))) float float4v;

__device__ __forceinline__ unsigned short f2bu(float v){
  __hip_bfloat16 h = __float2bfloat16(v);
  union { __hip_bfloat16 h; unsigned short u; } cv; cv.h = h; return cv.u;
}

// soft(v, lam) = sign(v) * max(|v| - lam, 0)   (lam may be negative)
__device__ __forceinline__ float softt(float v, float lam){
  float t = fmaxf(fabsf(v) - lam, 0.f);
  float r = copysignf(t, v);
  return (v == 0.f) ? 0.f : r;
}

// L scalar (f32 input)
__global__ void k_Lin(const float* __restrict__ Lsrc, float* __restrict__ Lb){
  Lb[0] = Lsrc[0];
}

// Gram in bf16: Gb[j][a] = bf16(sum_c D[c][j]*D[c][a]).
__global__ void k_gram(const float* __restrict__ D, unsigned short* __restrict__ Gb){
  int j = blockIdx.x, a = threadIdx.x;
  float acc = 0.f;
  for (int c = 0; c < 64; ++c)
    acc += D[c*256 + j] * D[c*256 + a];
  Gb[j*256 + a] = f2bu(acc);
}

// DT[a][c] = D[c][a] (f32 for recon) + bf16 copy
__global__ void k_transpD(const float* __restrict__ D, float* __restrict__ DT,
                          unsigned short* __restrict__ DTb){
  int gid = blockIdx.x * 256 + threadIdx.x;     // gid = a*64 + c
  if (gid < 16384) {
    int a = gid >> 6, c = gid & 63;
    float v = D[c*256 + a];
    DT[gid] = v;
    DTb[gid] = f2bu(v);
  }
}

// fp32 -> bf16 cast (1x1 conv weights [O][I], and x -> xb)
__global__ void k_castw(const float* __restrict__ w, unsigned short* __restrict__ wb,
                        int n){
  int gid = blockIdx.x * 256 + threadIdx.x;
  if (gid < n) wb[gid] = f2bu(w[gid]);
}

// 3x3 conv weights OIHW f32 -> tap-major bf16 [O][9][I]
__global__ void k_permw3(const float* __restrict__ w, unsigned short* __restrict__ wb,
                         int logI, int n){
  int gid = blockIdx.x * 256 + threadIdx.x;
  if (gid >= n) return;
  int I = 1 << logI;
  int i = gid & (I - 1);
  int t = gid >> logI;        // o*9 + r
  int o = t / 9;
  int r = t - o * 9;
  wb[gid] = f2bu(w[((o << logI) + i) * 9 + r]);
}

// ---------------------------------------------------------------------------
// MFMA implicit-GEMM conv: bf16 activations (relu pre-applied by producer),
// tap-major bf16 weights [O][KS*KS][CIN], fp32 accumulate.
// BM=64 (one image row), BN templated (128 or 64), BK=64, 256 thr / 4 waves.
// BN=64 doubles the grid for Cout=128 convs -> 4 blocks/CU (latency hiding).
// K-slice order identical in all configs -> bitwise-identical accumulation.
// 1-deep register prefetch; XCD-aware block swizzle (grid.x % 8 == 0).
// ---------------------------------------------------------------------------
template<int KS, int CIN, int BN, bool BIAS, bool RES, bool WF32, bool WBF>
__global__ __launch_bounds__(256) void k_conv(
    const unsigned short* __restrict__ in, const unsigned short* __restrict__ wb,
    const float* __restrict__ bias, const float* res, float* outf,
    unsigned short* __restrict__ outb, int Cout)
{
  constexpr int TPC   = CIN / 64;            // 64-wide k-chunks per tap
  constexpr int K     = KS * KS * CIN;
  constexpr int LOGBN = (BN == 128) ? 7 : 6;
  constexpr int BCH   = BN / 32;             // short8v per thread (B stage)
  constexpr int NT    = BN / 64;             // 16-col tiles per wave

  __shared__ unsigned short Asb[64][72];     // row stride 144 B
  __shared__ unsigned short Bsb[BN][72];

  const int tid = threadIdx.x;
  int bx = blockIdx.x;
  { const int cpx = gridDim.x >> 3; bx = (bx & 7) * cpx + (bx >> 3); }
  const int m0  = bx * 64;
  const int n0  = blockIdx.y * BN;
  const int b   = m0 >> 12;
  const int hw0 = m0 & 4095;
  const int h   = hw0 >> 6;
  const int w0  = hw0 & 63;

  // staging assignments
  const int sm  = tid & 63;                  // A row (m, spatial w)
  const int sq8 = tid >> 6;                  // A 8-k chunk 0..3 (+4 for hi half)
  const int bn  = tid & (BN - 1);            // B row (n-local)
  const int bq  = tid >> LOGBN;              // B k-group

  // MFMA lane mapping
  const int w   = tid >> 6;                  // wave 0..3
  const int ln  = tid & 63;
  const int q   = ln >> 4;
  const int l16 = ln & 15;

  float4v acc[NT][4];
  #pragma unroll
  for (int nt = 0; nt < NT; ++nt)
    #pragma unroll
    for (int mt = 0; mt < 4; ++mt)
      acc[nt][mt] = (float4v){0.f, 0.f, 0.f, 0.f};

  int sA = 0, sB = TPC;
  if (KS == 3) { sA = (h == 0 ? 3 : 0) * TPC; sB = (h == 63 ? 6 : 9) * TPC; }

  short8v a_r0, a_r1;
  short8v b_r[4];

  auto pref = [&](int s){
    const int r   = s / TPC;                 // tap
    const int c64 = s - r * TPC;
    int hh = h, ww = w0 + sm;
    bool ok = true;
    if (KS == 3) {
      const int r3 = r / 3;
      const int dw = r - r3 * 3 - 1;
      hh = h + r3 - 1;
      ww += dw;
      ok = ((unsigned)ww < 64u);
    }
    a_r0 = (short8v){0,0,0,0,0,0,0,0};
    a_r1 = (short8v){0,0,0,0,0,0,0,0};
    if (ok) {
      const unsigned short* ap = in +
          (((size_t)(b * CIN + c64 * 64 + sq8 * 8)) << 12) + (hh << 6) + ww;
      #pragma unroll
      for (int j = 0; j < 8; ++j)
        a_r0[j] = (short)ap[(size_t)j << 12];
      const unsigned short* ap2 = ap + ((size_t)32 << 12);
      #pragma unroll
      for (int j = 0; j < 8; ++j)
        a_r1[j] = (short)ap2[(size_t)j << 12];
    }
    const unsigned short* bp = wb + (size_t)(n0 + bn) * K + s * 64 + bq * (BCH * 8);
    #pragma unroll
    for (int j = 0; j < BCH; ++j)
      b_r[j] = *(const short8v*)(bp + j * 8);
  };

  pref(sA);
  for (int s = sA; s < sB; ) {
    // commit prefetched tile to LDS
    *(short8v*)(&Asb[sm][sq8 * 8])       = a_r0;
    *(short8v*)(&Asb[sm][32 + sq8 * 8])  = a_r1;
    #pragma unroll
    for (int j = 0; j < BCH; ++j)
      *(short8v*)(&Bsb[bn][bq * (BCH * 8) + j * 8]) = b_r[j];
    __syncthreads();
    const int sn = s + 1;
    if (sn < sB) pref(sn);               // loads in flight across the MFMAs
    short8v Af[4][2];
    #pragma unroll
    for (int mt = 0; mt < 4; ++mt) {
      Af[mt][0] = *(const short8v*)(&Asb[mt * 16 + l16][q * 8]);
      Af[mt][1] = *(const short8v*)(&Asb[mt * 16 + l16][32 + q * 8]);
    }
    #pragma unroll
    for (int nt = 0; nt < NT; ++nt) {
      const int nr = w * (BN / 4) + nt * 16 + l16;
      const short8v Bf0 = *(const short8v*)(&Bsb[nr][q * 8]);
      const short8v Bf1 = *(const short8v*)(&Bsb[nr][32 + q * 8]);
      #pragma unroll
      for (int mt = 0; mt < 4; ++mt) {
        acc[nt][mt] = __builtin_amdgcn_mfma_f32_16x16x32_bf16(
            Af[mt][0], Bf0, acc[nt][mt], 0, 0, 0);
        acc[nt][mt] = __builtin_amdgcn_mfma_f32_16x16x32_bf16(
            Af[mt][1], Bf1, acc[nt][mt], 0, 0, 0);
      }
    }
    __syncthreads();
    s = sn;
  }

  // ---- epilogue: C row=q*4+r (spatial m), col=l16 (n)
  #pragma unroll
  for (int nt = 0; nt < NT; ++nt) {
    const int n = n0 + w * (BN / 4) + nt * 16 + l16;
    float bv = 0.f;
    if (BIAS) bv = bias[n];
    #pragma unroll
    for (int mt = 0; mt < 4; ++mt) {
      const size_t base = (((size_t)(b * Cout + n)) << 12) + hw0 + mt * 16 + q * 4;
      float o[4];
      #pragma unroll
      for (int r2 = 0; r2 < 4; ++r2) o[r2] = acc[nt][mt][r2] + bv;
      if (RES) {
        float4 r4 = *(const float4*)(res + base);
        o[0] += r4.x; o[1] += r4.y; o[2] += r4.z; o[3] += r4.w;
      }
      if (WF32) {
        float4 o4; o4.x = o[0]; o4.y = o[1]; o4.z = o[2]; o4.w = o[3];
        *(float4*)(outf + base) = o4;
      }
      if (WBF) {
        short4v s4;
        #pragma unroll
        for (int r2 = 0; r2 < 4; ++r2) s4[r2] = (short)f2bu(fmaxf(o[r2], 0.f));
        *(short4v*)(outb + base) = s4;
      }
    }
  }
}

// ---------------------------------------------------------------------------
// CBAM
// ---------------------------------------------------------------------------
__global__ void k_pool(const float* __restrict__ l, float* __restrict__ avg,
                       float* __restrict__ mx){
  int b = blockIdx.y, a = blockIdx.x, tid = threadIdx.x;
  const float* p = l + ((size_t)(b * 256 + a) << 12);
  float s = 0.f, m = -1e30f;
  for (int i = tid; i < 4096; i += 256) { float v = p[i]; s += v; m = fmaxf(m, v); }
  __shared__ float ss[256], sm[256];
  ss[tid] = s; sm[tid] = m; __syncthreads();
  for (int o = 128; o > 0; o >>= 1) {
    if (tid < o) { ss[tid] += ss[tid+o]; sm[tid] = fmaxf(sm[tid], sm[tid+o]); }
    __syncthreads();
  }
  if (tid == 0) { avg[b*256+a] = ss[0] * (1.f/4096.f); mx[b*256+a] = sm[0]; }
}

__global__ void k_ca(const float* __restrict__ avg, const float* __restrict__ mx,
                     const float* __restrict__ w1, const float* __restrict__ w2,
                     float* __restrict__ cscale){
  int b = blockIdx.x, tid = threadIdx.x;
  __shared__ float h[16];
  if (tid < 16) {
    float sa = 0.f, sm = 0.f;
    for (int a = 0; a < 256; ++a) {
      float w = w1[tid*256 + a];
      sa += avg[b*256 + a] * w;
      sm += mx[b*256 + a] * w;
    }
    h[tid] = fmaxf(sa, 0.f) + fmaxf(sm, 0.f);
  }
  __syncthreads();
  float s = 0.f;
  for (int j = 0; j < 16; ++j) s += h[j] * w2[tid*16 + j];
  cscale[b*256 + tid] = 1.f / (1.f + __expf(-s));
}

__global__ void k_s2(const float* __restrict__ l, const float* __restrict__ cscale,
                     float* __restrict__ s2){
  int b = blockIdx.y;
  int hw = blockIdx.x * 256 + threadIdx.x;
  const float* p  = l + (((size_t)b * 256) << 12) + hw;
  const float* cs = cscale + b * 256;
  float s = 0.f, m = -1e30f;
  for (int a = 0; a < 256; ++a) {
    float v = p[(size_t)a << 12] * cs[a];
    s += v; m = fmaxf(m, v);
  }
  s2[((b*2) << 12) + hw]   = s * (1.f/256.f);
  s2[((b*2+1) << 12) + hw] = m;
}

__global__ void k_sa(const float* __restrict__ s2, const float* __restrict__ w,
                     float* __restrict__ sa){
  int b = blockIdx.y;
  int hw = blockIdx.x * 256 + threadIdx.x;
  int h = hw >> 6, ww = hw & 63;
  float acc = 0.f;
  for (int ch = 0; ch < 2; ++ch)
    for (int dh = -1; dh <= 1; ++dh)
      for (int dw = -1; dw <= 1; ++dw) {
        int hh = h + dh, wc = ww + dw;
        if ((unsigned)hh < 64u && (unsigned)wc < 64u)
          acc += s2[((b*2+ch) << 12) + (hh << 6) + wc] * w[ch*9 + (dh+1)*3 + (dw+1)];
      }
  sa[(b << 12) + hw] = 1.f / (1.f + __expf(-acc));
}

// ---------------------------------------------------------------------------
// FUSED LISTA (exact round-6 version: 100 us, VGPR=116, conflicts 2.4M).
// C' = S . z^T, S symmetric.  16 positions x 256 atoms; 256 thr / 4 waves;
// wave owns 64 atoms.  Sg[4][8] pinned via in-loop asm; zbuf 512B rows +
// XOR-8 chunk swizzle; launch_bounds(256,2) (NOT 4: that forces Sg to
// scratch -> 7 GB memory traffic, round-7 post-mortem).
// ---------------------------------------------------------------------------
#define XTS 80

__device__ __forceinline__ int zoff(int pos, int au8){
  return pos * 256 + (((au8 ^ (pos & 15)) & 31) << 3);
}

__global__ __launch_bounds__(256, 2) void k_lista(
    const unsigned short* __restrict__ xb,
    const unsigned short* __restrict__ DTb,
    const unsigned short* __restrict__ Gb,
    const float* __restrict__ lmap, const float* __restrict__ csc,
    const float* __restrict__ sav, const float* __restrict__ Lb,
    float* __restrict__ zout)
{
  __shared__ unsigned short zbuf[2][16 * 256];   // 16 KB total

  const int tid = threadIdx.x;
  const int m0  = blockIdx.x * 16;
  const int b   = m0 >> 12;
  const int hw0 = m0 & 4095;
  const float invL = 1.0f / Lb[0];

  // stage x tile (bf16, transposed) into zbuf[1] space: xTb[i*XTS + c]
  unsigned short* xTb = &zbuf[1][0];
  {
    const int i  = tid & 15;
    const int c0 = tid >> 4;          // 0..15
    #pragma unroll
    for (int cc = 0; cc < 4; ++cc) {
      int c = c0 + cc * 16;
      xTb[i * XTS + c] = xb[((b * 64 + c) << 12) + hw0 + i];
    }
  }

  const int w   = tid >> 6;           // wave 0..3 -> atoms w*64..w*64+63
  const int ln  = tid & 63;
  const int q   = ln >> 4;
  const int l16 = ln & 15;

  // persistent Gram A-fragments: 4 x 16-atom blocks x K=256 (128 VGPRs)
  short8v Sg[4][8];
  #pragma unroll
  for (int at = 0; at < 4; ++at)
    #pragma unroll
    for (int ks = 0; ks < 8; ++ks)
      Sg[at][ks] = *(const short8v*)(
          Gb + (size_t)(w * 64 + at * 16 + l16) * 256 + ks * 32 + q * 8);

  __syncthreads();   // xTb ready

  float z[4][4], yl[4][4], lamr[4][4];   // [at][r]

  // ---- prologue: y^T = D^T x^T ; lam fused ; z0 -> zbuf[0]
  {
    const short8v B0 = *(const short8v*)(&xTb[l16 * XTS + q * 8]);
    const short8v B1 = *(const short8v*)(&xTb[l16 * XTS + 32 + q * 8]);
    #pragma unroll
    for (int at = 0; at < 4; ++at) {
      const int abase = w * 64 + at * 16;
      const short8v A0 = *(const short8v*)(DTb + (abase + l16) * 64 + q * 8);
      const short8v A1 = *(const short8v*)(DTb + (abase + l16) * 64 + 32 + q * 8);
      float4v a = {0.f, 0.f, 0.f, 0.f};
      a = __builtin_amdgcn_mfma_f32_16x16x32_bf16(A0, B0, a, 0, 0, 0);
      a = __builtin_amdgcn_mfma_f32_16x16x32_bf16(A1, B1, a, 0, 0, 0);
      short4v pk;
      #pragma unroll
      for (int r = 0; r < 4; ++r) {
        const int atom = abase + q * 4 + r;
        const float lv = lmap[(((size_t)(b * 256 + atom)) << 12) + hw0 + l16];
        const float sv = sav[(b << 12) + hw0 + l16];
        const float cv = csc[b * 256 + atom];
        const float lm = ((lv * cv) * sv) * invL;   // same op order as before
        const float yv = a[r];
        lamr[at][r] = lm;
        yl[at][r]   = yv * invL;
        const float z0 = softt(yv, lm);
        z[at][r] = z0;
        pk[r] = (short)f2bu(z0);
      }
      *(short4v*)(&zbuf[0][zoff(l16, w * 8 + at * 2 + (q >> 1)) + (q & 1) * 4]) = pk;
    }
  }
  __syncthreads();

  int cur = 0;
  for (int it = 0; it < 16; ++it) {
    // pin Sg every iteration: reload-from-Gb would break the asm dataflow
    #pragma unroll
    for (int at = 0; at < 4; ++at)
      #pragma unroll
      for (int ks = 0; ks < 8; ++ks)
        asm volatile("" : "+v"(Sg[at][ks]));

    float4v acc[4];
    #pragma unroll
    for (int at = 0; at < 4; ++at)
      acc[at] = (float4v){0.f, 0.f, 0.f, 0.f};

    #pragma unroll
    for (int ks = 0; ks < 8; ++ks) {
      const short8v B = *(const short8v*)(&zbuf[cur][zoff(l16, ks * 4 + q)]);
      acc[0] = __builtin_amdgcn_mfma_f32_16x16x32_bf16(Sg[0][ks], B, acc[0], 0, 0, 0);
      acc[1] = __builtin_amdgcn_mfma_f32_16x16x32_bf16(Sg[1][ks], B, acc[1], 0, 0, 0);
      acc[2] = __builtin_amdgcn_mfma_f32_16x16x32_bf16(Sg[2][ks], B, acc[2], 0, 0, 0);
      acc[3] = __builtin_amdgcn_mfma_f32_16x16x32_bf16(Sg[3][ks], B, acc[3], 0, 0, 0);
    }

    #pragma unroll
    for (int at = 0; at < 4; ++at) {
      short4v pk;
      #pragma unroll
      for (int r = 0; r < 4; ++r) {
        const float u  = fmaf(-invL, acc[at][r], z[at][r] + yl[at][r]);
        const float nz = softt(u, lamr[at][r]);
        z[at][r] = nz;
        pk[r] = (short)f2bu(nz);
      }
      *(short4v*)(&zbuf[cur ^ 1][zoff(l16, w * 8 + at * 2 + (q >> 1)) + (q & 1) * 4]) = pk;
    }
    __syncthreads();
    cur ^= 1;
  }

  // ---- store z (f32, row-major [p][a]) as float4 (4 consecutive atoms)
  #pragma unroll
  for (int at = 0; at < 4; ++at) {
    float4 o;
    o.x = z[at][0]; o.y = z[at][1]; o.z = z[at][2]; o.w = z[at][3];
    *(float4*)(&zout[(size_t)(m0 + l16) * 256 + w * 64 + at * 16 + q * 4]) = o;
  }
}

// x_recon[p][c] = sum_a z[p][a]*DT[a][c] -> out1 (NCHW), AND out0 (NCHW z)
// fused from the same LDS tile (one 32MB z read instead of two).
__global__ __launch_bounds__(256) void k_recon_out(
    const float* __restrict__ z, const float* __restrict__ DT,
    float* __restrict__ out1, float* __restrict__ out0)
{
  __shared__ float zs[16][257];
  const int tid = threadIdx.x;
  const int r0  = blockIdx.x * 16;
  const int b   = r0 >> 12;
  const int hw0 = r0 & 4095;

  for (int idx = tid; idx < 4096; idx += 256) {
    int r = idx >> 8, k = idx & 255;
    zs[r][k] = z[(r0 + r) * 256 + k];
  }
  __syncthreads();

  // out0: z transposed to [b][a][hw] (16 consecutive hw per atom row)
  for (int idx = tid; idx < 1024; idx += 256) {
    const int a  = idx >> 2;
    const int rr = (idx & 3) * 4;
    float4 o;
    o.x = zs[rr][a]; o.y = zs[rr+1][a]; o.z = zs[rr+2][a]; o.w = zs[rr+3][a];
    *(float4*)(&out0[(((size_t)(b * 256 + a)) << 12) + hw0 + rr]) = o;
  }

  // recon
  const int c  = tid & 63;
  const int rg = tid >> 6;
  float acc[4] = {0.f, 0.f, 0.f, 0.f};
  for (int a = 0; a < 256; ++a) {
    float d = DT[a * 64 + c];
    #pragma unroll
    for (int i = 0; i < 4; ++i) acc[i] += zs[rg + 4*i][a] * d;
  }
  #pragma unroll
  for (int i = 0; i < 4; ++i) {
    int r = rg + 4*i;
    out1[((b * 64 + c) << 12) + hw0 + r] = acc[i];
  }
}

__global__ void k_dictout_f32(const float* __restrict__ D, float* __restrict__ out2){
  int i = blockIdx.x * 256 + threadIdx.x;
  if (i < 16384) out2[i] = D[i];
}

// ---------------------------------------------------------------------------
extern "C" void kernel_launch(void* const* d_in, const int* in_sizes, int n_in,
                              void* d_out, int out_size, void* d_ws, size_t ws_size,
                              hipStream_t stream)
{
  (void)in_sizes; (void)n_in; (void)out_size; (void)ws_size;

  const float* x    = (const float*)d_in[0];
  const float* cw   = (const float*)d_in[1];
  const float* cb   = (const float*)d_in[2];
  const float* r1w1 = (const float*)d_in[3];
  const float* r1w2 = (const float*)d_in[4];
  const float* r2w1 = (const float*)d_in[5];
  const float* r2w2 = (const float*)d_in[6];
  const float* caw1 = (const float*)d_in[7];
  const float* caw2 = (const float*)d_in[8];
  const float* saw  = (const float*)d_in[9];
  const float* D    = (const float*)d_in[10];
  const float* Lsrc = (const float*)d_in[11];

  float* p = (float*)d_ws;
  float* DT   = p; p += 16384;
  float* Lb   = p; p += 8;
  unsigned short* Gb  = (unsigned short*)p; p += 32768;   // 65536 bf16
  unsigned short* DTb = (unsigned short*)p; p += 8192;    // 16384 bf16
  unsigned short* cwb   = (unsigned short*)p; p += 73728;   // [256][9][64]
  unsigned short* r1w1b = (unsigned short*)p; p += 147456;  // [128][9][256]
  unsigned short* r1w2b = (unsigned short*)p; p += 16384;   // [256][128]
  unsigned short* r2w1b = (unsigned short*)p; p += 147456;
  unsigned short* r2w2b = (unsigned short*)p; p += 16384;
  float* avg  = p; p += 2048;
  float* mx   = p; p += 2048;
  float* csc  = p; p += 2048;
  float* s2   = p; p += 65536;
  float* sa   = p; p += 32768;
  float* l    = p; p += 8388608;
  float* scr  = p; p += 8388608;   // bf16 activation scratch region
  float* zt   = p; p += 8388608;   // final z
  float* z    = zt;

  // bf16 activation scratch (dead by the time k_lista runs, except xb which
  // is only ever written once by k_castw):
  unsigned short* xb = (unsigned short*)scr;                       // 2,097,152 u16
  unsigned short* lb = (unsigned short*)(scr + 1048576);           // 8,388,608 u16
  unsigned short* tb = (unsigned short*)(scr + 1048576 + 4194304); // 4,194,304 u16

  float* out0 = (float*)d_out;               // z       [8,256,64,64]
  float* out1 = out0 + (size_t)8*256*4096;   // x_recon [8,64,64,64]
  float* out2 = out1 + (size_t)8*64*4096;    // Dict    [64,256]

  dim3 b256(256);

  k_Lin<<<dim3(1), dim3(1), 0, stream>>>(Lsrc, Lb);
  k_gram<<<dim3(256), b256, 0, stream>>>(D, Gb);
  k_transpD<<<dim3(64), b256, 0, stream>>>(D, DT, DTb);
  // weights: 3x3 -> tap-major bf16, 1x1 -> plain bf16; x -> bf16
  k_permw3<<<dim3(576),  b256, 0, stream>>>(cw,   cwb,   6, 147456);
  k_permw3<<<dim3(1152), b256, 0, stream>>>(r1w1, r1w1b, 8, 294912);
  k_castw <<<dim3(128),  b256, 0, stream>>>(r1w2, r1w2b, 32768);
  k_permw3<<<dim3(1152), b256, 0, stream>>>(r2w1, r2w1b, 8, 294912);
  k_castw <<<dim3(128),  b256, 0, stream>>>(r2w2, r2w2b, 32768);
  k_castw <<<dim3(8192), b256, 0, stream>>>(x, xb, 2097152);

  // conv trunk (bf16 MFMA, tap-major weights, bf16 activation chain, BK=64)
  // Cout=256 convs: BN=128, grid (512,2).  Cout=128 convs: BN=64, grid
  // (512,2) = 1024 blocks -> 4 blocks/CU (latency hiding).
  k_conv<3,  64, 128, true,  false, true,  true ><<<dim3(512, 2), b256, 0, stream>>>(
      xb, cwb, cb, (const float*)nullptr, l, lb, 256);
  k_conv<3, 256,  64, false, false, false, true ><<<dim3(512, 2), b256, 0, stream>>>(
      lb, r1w1b, (const float*)nullptr, (const float*)nullptr, (float*)nullptr, tb, 128);
  k_conv<1, 128, 128, false, true,  true,  true ><<<dim3(512, 2), b256, 0, stream>>>(
      tb, r1w2b, (const float*)nullptr, l, l, lb, 256);
  k_conv<3, 256,  64, false, false, false, true ><<<dim3(512, 2), b256, 0, stream>>>(
      lb, r2w1b, (const float*)nullptr, (const float*)nullptr, (float*)nullptr, tb, 128);
  k_conv<1, 128, 128, false, true,  true,  false><<<dim3(512, 2), b256, 0, stream>>>(
      tb, r2w2b, (const float*)nullptr, l, l, (unsigned short*)nullptr, 256);

  // CBAM
  k_pool<<<dim3(256, 8), b256, 0, stream>>>(l, avg, mx);
  k_ca<<<dim3(8), b256, 0, stream>>>(avg, mx, caw1, caw2, csc);
  k_s2<<<dim3(16, 8), b256, 0, stream>>>(l, csc, s2);
  k_sa<<<dim3(16, 8), b256, 0, stream>>>(s2, saw, sa);

  // FUSED LISTA (round-6 config: 256 threads, 4 waves, 64 atoms/wave)
  k_lista<<<dim3(2048), b256, 0, stream>>>(xb, DTb, Gb, l, csc, sa, Lb, z);

  // outputs (float32): recon + z-transpose fused (one z read pass)
  k_recon_out<<<dim3(2048), b256, 0, stream>>>(z, DT, out1, out0);
  k_dictout_f32<<<dim3(64), b256, 0, stream>>>(D, out2);
}